// Round 8
// baseline (249.094 us; speedup 1.0000x reference)
//
#include <hip/hip_runtime.h>

// B=4, H=W=64, D=256, N=8, K=V=32, H2=W2=32, HW=4096, M=1024 pooled/batch.

typedef _Float16 f16x8 __attribute__((ext_vector_type(8)));
typedef _Float16 f16x4 __attribute__((ext_vector_type(4)));
typedef float    f32x4 __attribute__((ext_vector_type(4)));

#define F16(x) static_cast<_Float16>(x)

#if __has_builtin(__builtin_amdgcn_exp2f)
#define EXP2(x) __builtin_amdgcn_exp2f(x)
#else
#define EXP2(x) exp2f(x)
#endif

// async global->LDS DMA, 16 B per lane; lane i lands at ldsbase + i*16
__device__ __forceinline__ void gl_lds16(const void* g, void* l) {
    __builtin_amdgcn_global_load_lds(
        (const __attribute__((address_space(1))) unsigned int*)g,
        (__attribute__((address_space(3))) unsigned int*)l, 16, 0, 0);
}

// ---------------- prep: weight transpose (f16) + 2x2 maxpool (f16) ---------
// blocks 0..767: wt[mat][o][d] = w[d][o]   (coalesced writes, gather reads)
// blocks 768..1791: pooled[m][d] = max 2x2 of blob, f16 [4096][256]
__global__ void prep_kernel(const float* __restrict__ wq, const float* __restrict__ wk,
                            const float* __restrict__ wv, _Float16* __restrict__ wt,
                            const float* __restrict__ blob, _Float16* __restrict__ pooled) {
    const int jb = blockIdx.x;
    if (jb < 768) {
        const int idx = jb * 256 + threadIdx.x;      // 196,608 exact
        const int mat = idx >> 16;
        const int r = idx & 65535;
        const int o = r >> 8, d = r & 255;           // d consecutive -> coalesced write
        const float* w = (mat == 0) ? wq : (mat == 1 ? wk : wv);
        wt[(mat << 16) + o * 256 + d] = (_Float16)w[d * 256 + o];
    } else {
        const int pi = (jb - 768) * 1024 + threadIdx.x * 4;   // 1,048,576 outs
        const int m = pi >> 8, d0 = pi & 255;
        const int bb = m >> 10, y = (m >> 5) & 31, x = m & 31;
        const float* p = blob + ((((bb * 64 + 2 * y) * 64) + 2 * x) << 8) + d0;
        const float4 a = *(const float4*)(p);
        const float4 bx = *(const float4*)(p + 256);
        const float4 c = *(const float4*)(p + 16384);
        const float4 dd = *(const float4*)(p + 16640);
        const float v0 = fmaxf(fmaxf(a.x, bx.x), fmaxf(c.x, dd.x));
        const float v1 = fmaxf(fmaxf(a.y, bx.y), fmaxf(c.y, dd.y));
        const float v2 = fmaxf(fmaxf(a.z, bx.z), fmaxf(c.z, dd.z));
        const float v3 = fmaxf(fmaxf(a.w, bx.w), fmaxf(c.w, dd.w));
        auto h0 = __builtin_amdgcn_cvt_pkrtz(v0, v1);
        auto h1 = __builtin_amdgcn_cvt_pkrtz(v2, v3);
        const f16x4 o4 = {F16(h0[0]), F16(h0[1]), F16(h1[0]), F16(h1[1])};
        *(f16x4*)(pooled + m * 256 + d0) = o4;
    }
}

// ---------------- proj: K and V 1x1-conv GEMMs (Q moved into attn) ----------
// block = 32 rows x 256 cols, 4 waves; wave = 32 rows x 64 cols (2 mc x 4 nt).
// job 0: K (dst [bn][i][32])           512 blocks
// job 1: V (swish, dst [bn][v][4096])  512 blocks
__global__ __launch_bounds__(256) void proj_kernel(
    const float* __restrict__ blob, const _Float16* __restrict__ wt,
    const float* __restrict__ bk, const float* __restrict__ bv,
    _Float16* __restrict__ ko, _Float16* __restrict__ vo) {
    const int lane = threadIdx.x & 63, wid = threadIdx.x >> 6;
    const int quad = lane >> 4, l16 = lane & 15;
    const int jb = blockIdx.x;
    const int job = (jb < 512) ? 0 : 1;
    const int rowblk = (jb < 512) ? jb : jb - 512;
    const int rowbase = rowblk * 32;
    const int colbase = wid * 64;
    const _Float16* wmat = wt + ((size_t)(job + 1) << 16);   // wt: [Q|K|V]
    const float* bias = (job == 0) ? bk : bv;

    f32x4 acc[2][4];
#pragma unroll
    for (int mc = 0; mc < 2; ++mc)
#pragma unroll
        for (int nt = 0; nt < 4; ++nt) acc[mc][nt] = (f32x4){0.f, 0.f, 0.f, 0.f};

    const float* a0[2];
#pragma unroll
    for (int mc = 0; mc < 2; ++mc)
        a0[mc] = blob + (size_t)(rowbase + mc * 16 + l16) * 256;

#pragma unroll 2
    for (int kc = 0; kc < 8; ++kc) {
        f16x8 bf[4];
#pragma unroll
        for (int nt = 0; nt < 4; ++nt)
            bf[nt] = *(const f16x8*)(wmat + (colbase + nt * 16 + l16) * 256 + kc * 32 + quad * 8);
#pragma unroll
        for (int mc = 0; mc < 2; ++mc) {
            const float* ap = a0[mc] + kc * 32 + quad * 8;
            const float4 f0 = *(const float4*)(ap);
            const float4 f1 = *(const float4*)(ap + 4);
            auto c0 = __builtin_amdgcn_cvt_pkrtz(f0.x, f0.y);
            auto c1 = __builtin_amdgcn_cvt_pkrtz(f0.z, f0.w);
            auto c2 = __builtin_amdgcn_cvt_pkrtz(f1.x, f1.y);
            auto c3 = __builtin_amdgcn_cvt_pkrtz(f1.z, f1.w);
            f16x8 af = {F16(c0[0]), F16(c0[1]), F16(c1[0]), F16(c1[1]),
                        F16(c2[0]), F16(c2[1]), F16(c3[0]), F16(c3[1])};
#pragma unroll
            for (int nt = 0; nt < 4; ++nt)
                acc[mc][nt] = __builtin_amdgcn_mfma_f32_16x16x32_f16(af, bf[nt], acc[mc][nt], 0, 0, 0);
        }
    }

#pragma unroll
    for (int nt = 0; nt < 4; ++nt) {
        const int o = colbase + nt * 16 + l16;
        const float bs = bias[o];
        const int nh = o >> 5, kk = o & 31;
#pragma unroll
        for (int mc = 0; mc < 2; ++mc) {
            if (job == 0) {
#pragma unroll
                for (int r = 0; r < 4; ++r) {
                    const int grow = rowbase + mc * 16 + quad * 4 + r;
                    const float x = acc[mc][nt][r] + bs;
                    const int bb = grow >> 12, ii = grow & 4095;
                    ko[(((bb * 8 + nh) * 4096 + ii) << 5) + kk] = (_Float16)x;
                }
            } else {
                const int grow0 = rowbase + mc * 16 + quad * 4;
                const int bb = grow0 >> 12, i0 = grow0 & 4095;
                f16x4 pv;
#pragma unroll
                for (int r = 0; r < 4; ++r) {
                    float x = acc[mc][nt][r] + bs;
                    const float sg = 1.0f / (1.0f + __expf(-x));
                    pv[r] = (_Float16)(x * sg);
                }
                *(f16x4*)(vo + (((size_t)(bb * 8 + nh) * 32 + kk) << 12) + i0) = pv;
            }
        }
    }
}

// ---------------- attn: fused Q-proj + barrier-free per-wave K/V pipeline ---
// grid 512 = 32 bn (XCD swizzle) x 16 mt; block = 8 waves (512 thr), 64 q-rows.
// Phase 0: Q[64][32] = pooled @ WqT for head n (8 waves: mc=wid>>1, ct=wid&1);
//          C-layout -> LDS -> B-operand frags qf[4].
// Phase 1: wave wid owns keys [wid*512,+512) with a PRIVATE double-buffered
//          16-key LDS tile (K 1 KB + V 1 KB per buffer). No barriers: each
//          wave syncs its own DMA with s_waitcnt vmcnt(2) (vmcnt(0) last).
// K granule (k,c):   slot k*4 + ((c + (k>>2))&3)  -> conflict-free b128 reads
// V granule (v,c2):  slot v*2 + ((c2 + (v>>2))&1) -> conflict-free b64 reads
__global__ __launch_bounds__(512, 6) void attn_kernel(
    const _Float16* __restrict__ pooled,  // [4096][256] f16
    const _Float16* __restrict__ wtq,     // [256 o][256 d] f16 (Q part of wt)
    const float* __restrict__ bq,
    const _Float16* __restrict__ kb,      // [32][4096][32]
    const _Float16* __restrict__ vt,      // [32][32][4096] (V^T)
    float* __restrict__ out) {            // [4][1024][256]
    __shared__ __align__(16) char tiles[32768];     // 8 waves x 4 KB
    __shared__ __align__(16) _Float16 Qs[64 * 40];  // Q staging, stride 40
    __shared__ float epi[64 * 33 + 64];             // num[64][33] + den[64]

    const int tid = threadIdx.x;
    const int lane = tid & 63, wid = tid >> 6;
    const int quad = lane >> 4, l16 = lane & 15;
    const int bn = blockIdx.x & 31, mt = blockIdx.x >> 5;
    const int b = bn >> 3, n = bn & 7;
    const int m0 = mt * 64;

    // ---- phase 0: Q tile for this (bn, mt) ----
    {
        const int mcq = wid >> 1, ct = wid & 1;
        f32x4 qacc = (f32x4){0.f, 0.f, 0.f, 0.f};
        const _Float16* arow = pooled + (size_t)((b << 10) + m0 + mcq * 16 + l16) * 256;
        const _Float16* brow = wtq + (size_t)(n * 32 + ct * 16 + l16) * 256;
#pragma unroll
        for (int kc = 0; kc < 8; ++kc) {
            const f16x8 af = *(const f16x8*)(arow + kc * 32 + quad * 8);
            const f16x8 bf = *(const f16x8*)(brow + kc * 32 + quad * 8);
            qacc = __builtin_amdgcn_mfma_f32_16x16x32_f16(af, bf, qacc, 0, 0, 0);
        }
        const float bsc = bq[n * 32 + ct * 16 + l16];
#pragma unroll
        for (int r = 0; r < 4; ++r) {
            // scale = (1/sqrt(32)) * log2(e): phase 1 uses exp2
            const float xq = (qacc[r] + bsc) * 0.25503508f;
            Qs[(mcq * 16 + quad * 4 + r) * 40 + ct * 16 + l16] = (_Float16)xq;
        }
    }
    __syncthreads();
    f16x8 qf[4];
#pragma unroll
    for (int mc = 0; mc < 4; ++mc)
        qf[mc] = *(const f16x8*)&Qs[(mc * 16 + l16) * 40 + quad * 8];
    for (int i = tid; i < 64 * 33 + 64; i += 512) epi[i] = 0.f;
    __syncthreads();   // zeros visible before any wave's epilogue atomics

    // ---- phase 1: barrier-free key loop ----
    char* wtile = tiles + wid * 4096;
    const int i00 = wid << 9;            // this wave's key base
    // DMA source lane addresses (swizzle inverses)
    const int gk = lane, kk_ = gk >> 2, ck = ((gk & 3) - (kk_ >> 2)) & 3;
    const _Float16* ksrc = kb + ((size_t)bn << 17) + (i00 + kk_) * 32 + ck * 8;
    const int gv = lane, vv = gv >> 1, cv = ((gv & 1) + (vv >> 2)) & 1;
    const _Float16* vsrc = vt + ((size_t)bn << 17) + vv * 4096 + i00 + cv * 8;

    // prologue: batch 0 -> buffer 0
    gl_lds16(ksrc, wtile);          ksrc += 512;
    gl_lds16(vsrc, wtile + 1024);   vsrc += 16;

    f32x4 acc[4][2];   // [mc][vc]: out^T[v=vc*16+quad*4+r][m=mc*16+l16]
#pragma unroll
    for (int mc = 0; mc < 4; ++mc) { acc[mc][0] = (f32x4){0.f,0.f,0.f,0.f}; acc[mc][1] = acc[mc][0]; }
    float ps[4] = {0.f, 0.f, 0.f, 0.f};

    const int koff = l16 * 64 + ((quad + (l16 >> 2)) & 3) * 16;
    const int voff = l16 * 32 + ((((quad >> 1) + (l16 >> 2)) & 1) << 4) + (quad & 1) * 8;

#pragma unroll 2
    for (int s = 0; s < 32; ++s) {
        const int buf = (s & 1) << 11;
        if (s < 31) {
            const int nbuf = ((s + 1) & 1) << 11;
            gl_lds16(ksrc, wtile + nbuf);          ksrc += 512;
            gl_lds16(vsrc, wtile + nbuf + 1024);   vsrc += 16;
            asm volatile("s_waitcnt vmcnt(2)" ::: "memory");
        } else {
            asm volatile("s_waitcnt vmcnt(0)" ::: "memory");
        }
        const f16x8 kf = *(const f16x8*)(wtile + buf + koff);
        const f16x4 va0 = *(const f16x4*)(wtile + buf + 1024 + voff);
        const f16x4 va1 = *(const f16x4*)(wtile + buf + 1024 + 512 + voff);

        f16x4 pb[4];
#pragma unroll
        for (int mc = 0; mc < 4; ++mc) {
            f32x4 sc = __builtin_amdgcn_mfma_f32_16x16x32_f16(kf, qf[mc], (f32x4){0.f,0.f,0.f,0.f}, 0, 0, 0);
            const float p0 = EXP2(sc[0]), p1 = EXP2(sc[1]), p2 = EXP2(sc[2]), p3 = EXP2(sc[3]);
            ps[mc] += (p0 + p1) + (p2 + p3);
            auto e0 = __builtin_amdgcn_cvt_pkrtz(p0, p1);
            auto e1 = __builtin_amdgcn_cvt_pkrtz(p2, p3);
            pb[mc] = (f16x4){F16(e0[0]), F16(e0[1]), F16(e1[0]), F16(e1[1])};
        }
#pragma unroll
        for (int mc = 0; mc < 4; ++mc) {
            acc[mc][0] = __builtin_amdgcn_mfma_f32_16x16x16f16(va0, pb[mc], acc[mc][0], 0, 0, 0);
            acc[mc][1] = __builtin_amdgcn_mfma_f32_16x16x16f16(va1, pb[mc], acc[mc][1], 0, 0, 0);
        }
    }

    // ---- epilogue: 8-way key-split combine ----
    float* num = epi;            // [64][33]
    float* den = epi + 64 * 33;  // [64]
#pragma unroll
    for (int mc = 0; mc < 4; ++mc) {
        ps[mc] += __shfl_xor(ps[mc], 16);
        ps[mc] += __shfl_xor(ps[mc], 32);
    }
#pragma unroll
    for (int mc = 0; mc < 4; ++mc)
#pragma unroll
        for (int vc = 0; vc < 2; ++vc)
#pragma unroll
            for (int r = 0; r < 4; ++r)
                atomicAdd(&num[(mc * 16 + l16) * 33 + vc * 16 + quad * 4 + r], acc[mc][vc][r]);
    if (quad == 0) {
#pragma unroll
        for (int mc = 0; mc < 4; ++mc) atomicAdd(&den[mc * 16 + l16], ps[mc]);
    }
    __syncthreads();

    // store: 64 m x 32 v = 2048 f32 = 512 threads x one float4
    {
        const int mloc = tid >> 3, v4 = (tid & 7) * 4;
        const float inv = 1.0f / den[mloc];
        const float* nr = num + mloc * 33 + v4;
        float4 o = {nr[0] * inv, nr[1] * inv, nr[2] * inv, nr[3] * inv};
        *(float4*)(out + (((b << 10) + m0 + mloc) << 8) + n * 32 + v4) = o;
    }
}

// ---------------- launch -----------------------------------------------------
extern "C" void kernel_launch(void* const* d_in, const int* in_sizes, int n_in,
                              void* d_out, int out_size, void* d_ws, size_t ws_size,
                              hipStream_t stream) {
    const float* blob = (const float*)d_in[0];
    const float* wq = (const float*)d_in[1];
    const float* bq = (const float*)d_in[2];
    const float* wk = (const float*)d_in[3];
    const float* bk = (const float*)d_in[4];
    const float* wv = (const float*)d_in[5];
    const float* bv = (const float*)d_in[6];
    float* out = (float*)d_out;

    char* ws = (char*)d_ws;
    _Float16* wt = (_Float16*)(ws);                    //   393,216 B  [Q|K|V]
    _Float16* ko = (_Float16*)(ws + 393216);           // 8,388,608 B
    _Float16* vo = (_Float16*)(ws + 8781824);          // 8,388,608 B
    _Float16* po = (_Float16*)(ws + 17170432);         // 2,097,152 B (pooled f16)

    prep_kernel<<<1792, 256, 0, stream>>>(wq, wk, wv, wt, blob, po);
    proj_kernel<<<1024, 256, 0, stream>>>(blob, wt, bk, bv, ko, vo);
    attn_kernel<<<512, 512, 0, stream>>>(po, wt, bq, ko, vo, out);
}

// Round 9
// 175.151 us; speedup vs baseline: 1.4222x; 1.4222x over previous
//
#include <hip/hip_runtime.h>

// B=4, H=W=64, D=256, N=8, K=V=32, H2=W2=32, HW=4096, M=1024 pooled/batch.

typedef _Float16 f16x8 __attribute__((ext_vector_type(8)));
typedef _Float16 f16x4 __attribute__((ext_vector_type(4)));
typedef float    f32x4 __attribute__((ext_vector_type(4)));

#define F16(x) static_cast<_Float16>(x)

#if __has_builtin(__builtin_amdgcn_exp2f)
#define EXP2(x) __builtin_amdgcn_exp2f(x)
#else
#define EXP2(x) exp2f(x)
#endif

// async global->LDS DMA, 16 B per lane; lane i lands at ldsbase + i*16
__device__ __forceinline__ void gl_lds16(const void* g, void* l) {
    __builtin_amdgcn_global_load_lds(
        (const __attribute__((address_space(1))) unsigned int*)g,
        (__attribute__((address_space(3))) unsigned int*)l, 16, 0, 0);
}

// ---------------- prep: weights -> f16 transposed wt[mat][o][d] -------------
__global__ void prep_kernel(const float* __restrict__ wq, const float* __restrict__ wk,
                            const float* __restrict__ wv, _Float16* __restrict__ wt) {
    const int idx = blockIdx.x * 256 + threadIdx.x;   // 196,608 exact
    const int mat = idx >> 16;
    const int r = idx & 65535;
    const int o = r >> 8, d = r & 255;                // d consecutive -> coalesced write
    const float* w = (mat == 0) ? wq : (mat == 1 ? wk : wv);
    wt[(mat << 16) + o * 256 + d] = (_Float16)w[d * 256 + o];
}

// ---------------- pkv: fused maxpool + Q/K/V projections (blob read ONCE) ---
// grid 512 = b(4) x y'(32) x xh(4). Block: 32 blob rows (2 y-rows x 16 x),
// staged f32->f16 in LDS; pooled 8 rows in LDS; 8 waves:
//   waves 0-3: K cols [wid*64,+64);  waves 4-7: V cols [(wid-4)*64,+64);
//   every wave: Q cols [wid*32,+32) from pooled rows (8 valid of 16).
__global__ __launch_bounds__(512, 2) void pkv_kernel(
    const float* __restrict__ blob, const _Float16* __restrict__ wt,
    const float* __restrict__ bq, const float* __restrict__ bk, const float* __restrict__ bv,
    _Float16* __restrict__ qo, _Float16* __restrict__ ko, _Float16* __restrict__ vo) {
    __shared__ _Float16 As[32 * 264];
    __shared__ _Float16 Ps[16 * 264];   // rows 0..7 valid

    const int tid = threadIdx.x;
    const int lane = tid & 63, wid = tid >> 6;
    const int quad = lane >> 4, l16 = lane & 15;
    const int xh = blockIdx.x & 3, yp = (blockIdx.x >> 2) & 31, b = blockIdx.x >> 7;

    // ---- stage 32 rows x 256 f32 -> LDS f16 (coalesced 128B-per-8-lane) ----
    {
        const int rloc = tid >> 4;
        const int c0 = (tid & 15) * 4;
        const int yy = rloc >> 4, xx = rloc & 15;
        const float* grow = blob + (size_t)(b * 4096 + (2 * yp + yy) * 64 + xh * 16 + xx) * 256;
#pragma unroll
        for (int it = 0; it < 4; ++it) {
            const int c = c0 + it * 64;
            const float4 f = *(const float4*)(grow + c);
            auto h0 = __builtin_amdgcn_cvt_pkrtz(f.x, f.y);
            auto h1 = __builtin_amdgcn_cvt_pkrtz(f.z, f.w);
            *(f16x4*)&As[rloc * 264 + c] = (f16x4){F16(h0[0]), F16(h0[1]), F16(h1[0]), F16(h1[1])};
        }
    }
    __syncthreads();

    // ---- pool 8 rows (f16 max == f32 max then cvt: monotone, exact) ----
    {
        const int px = tid >> 6, co = (tid & 63) * 4;
        const f16x4 a = *(const f16x4*)&As[(2 * px) * 264 + co];
        const f16x4 b2 = *(const f16x4*)&As[(2 * px + 1) * 264 + co];
        const f16x4 c2 = *(const f16x4*)&As[(16 + 2 * px) * 264 + co];
        const f16x4 d2 = *(const f16x4*)&As[(17 + 2 * px) * 264 + co];
        f16x4 m;
#pragma unroll
        for (int r = 0; r < 4; ++r) {
            _Float16 t1 = a[r] > b2[r] ? a[r] : b2[r];
            _Float16 t2 = c2[r] > d2[r] ? c2[r] : d2[r];
            m[r] = t1 > t2 ? t1 : t2;
        }
        *(f16x4*)&Ps[px * 264 + co] = m;
    }
    __syncthreads();

    // ---- GEMMs ----
    const bool isV = wid >= 4;
    const int colb = (wid & 3) * 64;
    const _Float16* wm = wt + (isV ? 131072 : 65536);

    f32x4 acc[2][4], qacc[2];
#pragma unroll
    for (int mc = 0; mc < 2; ++mc)
#pragma unroll
        for (int nt = 0; nt < 4; ++nt) acc[mc][nt] = (f32x4){0.f, 0.f, 0.f, 0.f};
    qacc[0] = (f32x4){0.f, 0.f, 0.f, 0.f}; qacc[1] = qacc[0];

#pragma unroll
    for (int kc = 0; kc < 8; ++kc) {
        const int ko_ = kc * 32 + quad * 8;
        const f16x8 a0 = *(const f16x8*)&As[l16 * 264 + ko_];
        const f16x8 a1 = *(const f16x8*)&As[(16 + l16) * 264 + ko_];
        const f16x8 aq = *(const f16x8*)&Ps[l16 * 264 + ko_];
#pragma unroll
        for (int nt = 0; nt < 4; ++nt) {
            const f16x8 bf = *(const f16x8*)(wm + (colb + nt * 16 + l16) * 256 + ko_);
            acc[0][nt] = __builtin_amdgcn_mfma_f32_16x16x32_f16(a0, bf, acc[0][nt], 0, 0, 0);
            acc[1][nt] = __builtin_amdgcn_mfma_f32_16x16x32_f16(a1, bf, acc[1][nt], 0, 0, 0);
        }
#pragma unroll
        for (int ntq = 0; ntq < 2; ++ntq) {
            const f16x8 bf = *(const f16x8*)(wt + (wid * 32 + ntq * 16 + l16) * 256 + ko_);
            qacc[ntq] = __builtin_amdgcn_mfma_f32_16x16x32_f16(aq, bf, qacc[ntq], 0, 0, 0);
        }
    }

    // ---- K/V epilogue ----
#pragma unroll
    for (int nt = 0; nt < 4; ++nt) {
        const int o = colb + nt * 16 + l16;
        const int nh = o >> 5, kk = o & 31;
#pragma unroll
        for (int mc = 0; mc < 2; ++mc) {
            const int xx0 = quad * 4;                     // rloc = mc*16+quad*4+r
            const int i0g = (2 * yp + mc) * 64 + xh * 16 + xx0;
            if (!isV) {
                const float bs = bk[o];
#pragma unroll
                for (int r = 0; r < 4; ++r)
                    ko[(((size_t)(b * 8 + nh) * 4096 + i0g + r) << 5) + kk] = (_Float16)(acc[mc][nt][r] + bs);
            } else {
                const float bs = bv[o];
                f16x4 pv;
#pragma unroll
                for (int r = 0; r < 4; ++r) {
                    const float x = acc[mc][nt][r] + bs;
                    const float sg = 1.0f / (1.0f + __expf(-x));
                    pv[r] = (_Float16)(x * sg);
                }
                *(f16x4*)(vo + (((size_t)(b * 8 + nh) * 32 + kk) << 12) + i0g) = pv;
            }
        }
    }
    // ---- Q epilogue (valid pooled rows = 0..7 -> quads 0,1 only) ----
    if (quad < 2) {
#pragma unroll
        for (int ntq = 0; ntq < 2; ++ntq) {
            const int o = wid * 32 + ntq * 16 + l16;
            const int nh = o >> 5, kk = o & 31;
            const float bs = bq[o];
#pragma unroll
            for (int r = 0; r < 4; ++r) {
                const int px = quad * 4 + r;
                const int m = yp * 32 + xh * 8 + px;
                // scale = (1/sqrt(32)) * log2(e): attn uses exp2
                qo[(((b * 8 + nh) * 1024 + m) << 5) + kk] = (_Float16)((qacc[ntq][r] + bs) * 0.25503508f);
            }
        }
    }
}

// ---------------- attn: per-wave streams, drain-free pacing barrier ---------
// grid 512 = 32 bn (XCD swizzle) x 16 mt; 8 waves, block = 64 q-rows (shared).
// Wave wid: keys [wid*512,+512), private double-buffered 32-key tile
// (K 2 KB + V 2 KB per buffer). Own-DMA sync: s_waitcnt vmcnt(4) (0 on last);
// raw s_barrier per step ONLY for cross-block L2 phase-lock (no drain).
// K slot(k,c) = k*4 + ((c+(k>>2))&3)  -> conflict-free b128 reads.
// V: 16B-granule rotation by (v>>2)&1 -> ~2-way b64 reads.
// Denominator via ones-row MFMA (A=1 => C[i][m] = sum_k pb[k][m]).
__global__ __launch_bounds__(512, 4) void attn_kernel(
    const _Float16* __restrict__ qb,   // [32][1024][32] (pre-scaled log2e/sqrt32)
    const _Float16* __restrict__ kb,   // [32][4096][32]
    const _Float16* __restrict__ vt,   // [32][32][4096] (V^T)
    float* __restrict__ out) {         // [4][1024][256]
    __shared__ __align__(16) char tiles[65536];     // 8 waves x 2 bufs x 4 KB
    __shared__ float epi[64 * 33 + 64];             // num[64][33] + den[64]

    const int tid = threadIdx.x;
    const int lane = tid & 63, wid = tid >> 6;
    const int quad = lane >> 4, l16 = lane & 15;
    const int bn = blockIdx.x & 31, mt = blockIdx.x >> 5;
    const int b = bn >> 3, n = bn & 7;
    const int m0 = mt * 64;

    for (int i = tid; i < 64 * 33 + 64; i += 512) epi[i] = 0.f;
    __syncthreads();

    // Q fragments: all 64 block q-rows per wave (4 mc)
    f16x8 qf[4];
#pragma unroll
    for (int mc = 0; mc < 4; ++mc)
        qf[mc] = *(const f16x8*)(qb + (((bn << 10) + m0 + mc * 16 + l16) << 5) + quad * 8);

    // ---- DMA source lane addresses (swizzle inverses), j in {0,1} ----
    const int i00 = wid << 9;
    const int kk0 = lane >> 2, ck = ((lane & 3) - quad) & 3;
    const _Float16* ks0 = kb + ((size_t)bn << 17) + (i00 + kk0) * 32 + ck * 8;
    const _Float16* ks1 = ks0 + 16 * 32;                  // k += 16
    const int vv0 = lane >> 2, gg = (lane & 2) + (((lane & 1) + (quad & 1)) & 1);
    const _Float16* vs0 = vt + ((size_t)bn << 17) + vv0 * 4096 + i00 + gg * 8;
    const _Float16* vs1 = vs0 + 16 * 4096;                // v += 16

    char* kt = tiles + wid * 8192;
    // prologue: step 0 -> buffer 0
    gl_lds16(ks0, kt);          gl_lds16(ks1, kt + 1024);
    gl_lds16(vs0, kt + 2048);   gl_lds16(vs1, kt + 3072);
    ks0 += 1024; ks1 += 1024; vs0 += 32; vs1 += 32;

    f32x4 acc[4][2], accd[4];
#pragma unroll
    for (int mc = 0; mc < 4; ++mc) {
        acc[mc][0] = (f32x4){0.f, 0.f, 0.f, 0.f};
        acc[mc][1] = acc[mc][0];
        accd[mc] = acc[mc][0];
    }
    const f16x4 ones = {F16(1.0f), F16(1.0f), F16(1.0f), F16(1.0f)};

    const int koff = l16 * 64 + ((quad + (l16 >> 2)) & 3) * 16;
    const int voff = l16 * 64 + ((((quad >> 1) + (l16 >> 2)) & 1) << 4) + (quad & 1) * 8;

#pragma unroll 1
    for (int s = 0; s < 16; ++s) {
        const int bf = (s & 1) << 12;
        if (s < 15) {
            char* nb = kt + (((s + 1) & 1) << 12);
            gl_lds16(ks0, nb);          gl_lds16(ks1, nb + 1024);
            gl_lds16(vs0, nb + 2048);   gl_lds16(vs1, nb + 3072);
            ks0 += 1024; ks1 += 1024; vs0 += 32; vs1 += 32;
            asm volatile("s_waitcnt vmcnt(4)" ::: "memory");
        } else {
            asm volatile("s_waitcnt vmcnt(0)" ::: "memory");
        }
#pragma unroll
        for (int tloc = 0; tloc < 2; ++tloc) {
            const f16x8 kf = *(const f16x8*)(kt + bf + tloc * 1024 + koff);
            const f16x4 va0 = *(const f16x4*)(kt + bf + 2048 + tloc * 32 + voff);
            const f16x4 va1 = *(const f16x4*)(kt + bf + 2048 + 1024 + tloc * 32 + voff);
            f16x4 pb[4];
#pragma unroll
            for (int mc = 0; mc < 4; ++mc) {
                f32x4 sc = __builtin_amdgcn_mfma_f32_16x16x32_f16(kf, qf[mc], (f32x4){0.f, 0.f, 0.f, 0.f}, 0, 0, 0);
                const float p0 = EXP2(sc[0]), p1 = EXP2(sc[1]), p2 = EXP2(sc[2]), p3 = EXP2(sc[3]);
                auto e0 = __builtin_amdgcn_cvt_pkrtz(p0, p1);
                auto e1 = __builtin_amdgcn_cvt_pkrtz(p2, p3);
                pb[mc] = (f16x4){F16(e0[0]), F16(e0[1]), F16(e1[0]), F16(e1[1])};
            }
#pragma unroll
            for (int mc = 0; mc < 4; ++mc) {
                acc[mc][0] = __builtin_amdgcn_mfma_f32_16x16x16f16(va0, pb[mc], acc[mc][0], 0, 0, 0);
                acc[mc][1] = __builtin_amdgcn_mfma_f32_16x16x16f16(va1, pb[mc], acc[mc][1], 0, 0, 0);
                accd[mc]   = __builtin_amdgcn_mfma_f32_16x16x16f16(ones, pb[mc], accd[mc], 0, 0, 0);
            }
        }
        // pacing barrier (no drain): keeps same-bn blocks L2 phase-locked
        asm volatile("s_barrier" ::: "memory");
    }

    // ---- epilogue: 8-way key-split combine ----
    float* num = epi;            // [64][33]
    float* den = epi + 64 * 33;  // [64]
#pragma unroll
    for (int mc = 0; mc < 4; ++mc)
#pragma unroll
        for (int vc = 0; vc < 2; ++vc)
#pragma unroll
            for (int r = 0; r < 4; ++r)
                atomicAdd(&num[(mc * 16 + l16) * 33 + vc * 16 + quad * 4 + r], acc[mc][vc][r]);
    if (quad == 0) {
#pragma unroll
        for (int mc = 0; mc < 4; ++mc) atomicAdd(&den[mc * 16 + l16], accd[mc][0]);
    }
    __syncthreads();

    // store: 64 m x 32 v = 2048 f32 = 512 threads x one float4
    {
        const int mloc = tid >> 3, v4 = (tid & 7) * 4;
        const float inv = 1.0f / den[mloc];
        const float* nr = num + mloc * 33 + v4;
        float4 o = {nr[0] * inv, nr[1] * inv, nr[2] * inv, nr[3] * inv};
        *(float4*)(out + (((b << 10) + m0 + mloc) << 8) + n * 32 + v4) = o;
    }
}

// ---------------- launch -----------------------------------------------------
extern "C" void kernel_launch(void* const* d_in, const int* in_sizes, int n_in,
                              void* d_out, int out_size, void* d_ws, size_t ws_size,
                              hipStream_t stream) {
    const float* blob = (const float*)d_in[0];
    const float* wq = (const float*)d_in[1];
    const float* bq = (const float*)d_in[2];
    const float* wk = (const float*)d_in[3];
    const float* bk = (const float*)d_in[4];
    const float* wv = (const float*)d_in[5];
    const float* bv = (const float*)d_in[6];
    float* out = (float*)d_out;

    char* ws = (char*)d_ws;
    _Float16* wt = (_Float16*)(ws);                    //   393,216 B  [Q|K|V]
    _Float16* ko = (_Float16*)(ws + 393216);           // 8,388,608 B
    _Float16* vo = (_Float16*)(ws + 8781824);          // 8,388,608 B
    _Float16* qo = (_Float16*)(ws + 17170432);         // 2,097,152 B

    prep_kernel<<<768, 256, 0, stream>>>(wq, wk, wv, wt);
    pkv_kernel<<<512, 512, 0, stream>>>(blob, wt, bq, bk, bv, qo, ko, vo);
    attn_kernel<<<512, 512, 0, stream>>>(qo, ko, vo, out);
}